// Round 1
// baseline (1468.724 us; speedup 1.0000x reference)
//
#include <hip/hip_runtime.h>
#include <math.h>

// ---------------------------------------------------------------------------
// NetGlobGATFix: CNN(4 conv3x3+selu, avgpool) -> concat(gfeat,x) -> 5x GATConv
// (softmax attention over incoming edges incl self-loops, mean over heads)
// with selu + boundary fixes between layers.
//
// Strategy this round: correctness-first fp32.
//  - CSR-by-dst built per launch in d_ws (histogram/atomic, single-block scan,
//    atomic scatter). Avoids per-edge float atomics in aggregation.
//  - Tiled 64x64 LDS fp32 GEMM for h @ W.
//  - Per-(node,head) wave reductions for es/ed; per-(node,head) segment max.
//  - Aggregation: one dst node per block, C threads; p recomputed per edge
//    (es/ed/m per node only, no per-edge storage).
// ---------------------------------------------------------------------------

#define DEVFN static __device__ __forceinline__

DEVFN float selu_f(float v) {
    const float scale = 1.0507009873554805f;
    const float alpha = 1.6732632423543772f;
    return v > 0.f ? scale * v : scale * alpha * (expf(v) - 1.f);
}

DEVFN float lrelu02(float v) { return v > 0.f ? v : 0.2f * v; }

// ---------------- CNN ----------------
__global__ void conv3x3_selu(const float* __restrict__ in, const float* __restrict__ w,
                             const float* __restrict__ b, float* __restrict__ out,
                             int Cin, int Cout) {
    int t = blockIdx.x * blockDim.x + threadIdx.x;
    if (t >= Cout * 4096) return;
    int pix = t & 4095;
    int co  = t >> 12;
    int y = pix >> 6, x = pix & 63;
    float acc = b[co];
    for (int ci = 0; ci < Cin; ++ci) {
        const float* ip = in + ci * 4096;
        const float* wp = w + (co * Cin + ci) * 9;
#pragma unroll
        for (int ky = 0; ky < 3; ++ky) {
            int yy = y + ky - 1;
            if (yy < 0 || yy > 63) continue;
#pragma unroll
            for (int kx = 0; kx < 3; ++kx) {
                int xx = x + kx - 1;
                if (xx < 0 || xx > 63) continue;
                acc += ip[yy * 64 + xx] * wp[ky * 3 + kx];
            }
        }
    }
    out[t] = selu_f(acc);
}

__global__ void avgpool_c(const float* __restrict__ in, float* __restrict__ gfeat) {
    int c = blockIdx.x;            // 24 blocks
    int t = threadIdx.x;           // 256 threads
    float s = 0.f;
    for (int i = t; i < 4096; i += 256) s += in[c * 4096 + i];
#pragma unroll
    for (int off = 32; off >= 1; off >>= 1) s += __shfl_xor(s, off);
    __shared__ float red[4];
    int wave = t >> 6, lane = t & 63;
    if (lane == 0) red[wave] = s;
    __syncthreads();
    if (t == 0) gfeat[c] = (red[0] + red[1] + red[2] + red[3]) * (1.f / 4096.f);
}

// ---------------- node feature init + boundary masks ----------------
__global__ void build_h0(const float* __restrict__ x, const float* __restrict__ gfeat,
                         float* __restrict__ h0, unsigned* __restrict__ masks, int N) {
    int n = blockIdx.x * blockDim.x + threadIdx.x;
    if (n >= N) return;
    float x0 = x[n * 10 + 0], x1 = x[n * 10 + 1];
    unsigned mk = (x0 == 1.f ? 1u : 0u) | (x0 == 0.f ? 2u : 0u) |
                  (x1 == 0.f ? 4u : 0u) | (x1 == 1.f ? 8u : 0u);
    masks[n] = mk;
    float* hp = h0 + (size_t)n * 34;
#pragma unroll
    for (int j = 0; j < 24; ++j) hp[j] = gfeat[j];
#pragma unroll
    for (int j = 0; j < 10; ++j) hp[24 + j] = x[n * 10 + j];
}

// ---------------- CSR build ----------------
__global__ void count_dst(const int* __restrict__ ei, int* __restrict__ cnt, int E, int N) {
    int t = blockIdx.x * blockDim.x + threadIdx.x;
    if (t >= E + N) return;
    int dst = (t < E) ? ei[E + t] : (t - E);
    atomicAdd(&cnt[dst], 1);
}

__global__ void exscan_single(const int* __restrict__ cnt, int* __restrict__ indptr, int n) {
    __shared__ int sdata[256];
    __shared__ int run_s;
    int tid = threadIdx.x;
    if (tid == 0) { run_s = 0; indptr[0] = 0; }
    __syncthreads();
    for (int base = 0; base < n; base += 256) {
        int i = base + tid;
        int v = (i < n) ? cnt[i] : 0;
        sdata[tid] = v;
        __syncthreads();
        for (int off = 1; off < 256; off <<= 1) {
            int tmp = (tid >= off) ? sdata[tid - off] : 0;
            __syncthreads();
            sdata[tid] += tmp;
            __syncthreads();
        }
        if (i < n) indptr[i + 1] = run_s + sdata[tid];
        __syncthreads();
        if (tid == 0) run_s += sdata[255];
        __syncthreads();
    }
}

__global__ void copy_int(const int* __restrict__ a, int* __restrict__ b, int n) {
    int t = blockIdx.x * blockDim.x + threadIdx.x;
    if (t < n) b[t] = a[t];
}

__global__ void scatter_edges(const int* __restrict__ ei, int* __restrict__ cursor,
                              int* __restrict__ col, int E, int N) {
    int t = blockIdx.x * blockDim.x + threadIdx.x;
    if (t >= E + N) return;
    int src, dst;
    if (t < E) { src = ei[t]; dst = ei[E + t]; }
    else       { src = dst = t - E; }
    int pos = atomicAdd(&cursor[dst], 1);
    col[pos] = src;
}

// ---------------- GEMM: C[N,M] = A[N,K] @ B[K,M], fp32, row-major packed ----
#define BN 64
#define BM 64
#define BK 16
__global__ __launch_bounds__(256) void sgemm(const float* __restrict__ A,
                                             const float* __restrict__ B,
                                             float* __restrict__ Cm,
                                             int N, int K, int M) {
    __shared__ float As[BK][BN + 1];
    __shared__ float Bs[BK][BM + 1];
    int tid = threadIdx.x;
    int tx = tid & 15, ty = tid >> 4;
    int row0 = blockIdx.x * BN;
    int col0 = blockIdx.y * BM;
    float acc[4][4] = {};
    for (int k0 = 0; k0 < K; k0 += BK) {
        for (int idx = tid; idx < BN * BK; idx += 256) {
            int i = idx >> 4, k = idx & 15;
            int r = row0 + i, kk = k0 + k;
            As[k][i] = (r < N && kk < K) ? A[(size_t)r * K + kk] : 0.f;
        }
        for (int idx = tid; idx < BK * BM; idx += 256) {
            int k = idx >> 6, j = idx & 63;
            int kk = k0 + k, cc = col0 + j;
            Bs[k][j] = (kk < K && cc < M) ? B[(size_t)kk * M + cc] : 0.f;
        }
        __syncthreads();
#pragma unroll
        for (int k = 0; k < BK; ++k) {
            float a[4], bv[4];
#pragma unroll
            for (int ii = 0; ii < 4; ++ii) a[ii] = As[k][ty * 4 + ii];
#pragma unroll
            for (int jj = 0; jj < 4; ++jj) bv[jj] = Bs[k][tx * 4 + jj];
#pragma unroll
            for (int ii = 0; ii < 4; ++ii)
#pragma unroll
                for (int jj = 0; jj < 4; ++jj) acc[ii][jj] += a[ii] * bv[jj];
        }
        __syncthreads();
    }
#pragma unroll
    for (int ii = 0; ii < 4; ++ii) {
        int r = row0 + ty * 4 + ii;
        if (r >= N) continue;
#pragma unroll
        for (int jj = 0; jj < 4; ++jj) {
            int c = col0 + tx * 4 + jj;
            if (c < M) Cm[(size_t)r * M + c] = acc[ii][jj];
        }
    }
}

// ---------------- es/ed: per (node, head) dot products ----------------
__global__ void esed_kernel(const float* __restrict__ hmid, const float* __restrict__ as,
                            const float* __restrict__ ad, float* __restrict__ es,
                            float* __restrict__ ed, int H, int C) {
    int b = blockIdx.x;            // n*H + h
    int h = b % H;
    int lane = threadIdx.x;        // 64
    const float* hp = hmid + (size_t)b * C;   // (n*H + h) * C
    float s = 0.f, d = 0.f;
    for (int c = lane; c < C; c += 64) {
        float v = hp[c];
        s += v * as[h * C + c];
        d += v * ad[h * C + c];
    }
#pragma unroll
    for (int off = 32; off >= 1; off >>= 1) {
        s += __shfl_xor(s, off);
        d += __shfl_xor(d, off);
    }
    if (lane == 0) { es[b] = s; ed[b] = d; }
}

// ---------------- segment max over incoming edges ----------------
__global__ void segmax_kernel(const float* __restrict__ es, const float* __restrict__ ed,
                              const int* __restrict__ indptr, const int* __restrict__ col,
                              float* __restrict__ mx, int N, int H) {
    int t = blockIdx.x * blockDim.x + threadIdx.x;
    if (t >= N * H) return;
    int n = t / H, h = t - n * H;
    float edv = ed[t];
    float mv = -3.4e38f;
    int beg = indptr[n], end = indptr[n + 1];
    for (int i = beg; i < end; ++i) {
        float e = lrelu02(es[col[i] * H + h] + edv);
        mv = fmaxf(mv, e);
    }
    mx[t] = mv;
}

// ---------------- GAT aggregation (C >= 64 layers): one node per block ------
template <int H, int C>
__global__ void gat_agg(const float* __restrict__ hmid, const float* __restrict__ es,
                        const float* __restrict__ ed, const float* __restrict__ mx,
                        const int* __restrict__ indptr, const int* __restrict__ col,
                        const float* __restrict__ bias, const unsigned* __restrict__ masks,
                        float* __restrict__ hout) {
    int n = blockIdx.x;
    int c = threadIdx.x;           // blockDim = C, C >= H
    __shared__ float p_sh[H], ed_sh[H], m_sh[H], z_sh[H];
    if (c < H) {
        ed_sh[c] = ed[n * H + c];
        m_sh[c]  = mx[n * H + c];
    }
    float acc[H];
#pragma unroll
    for (int h = 0; h < H; ++h) acc[h] = 0.f;
    float z = 0.f;
    __syncthreads();
    int beg = indptr[n], end = indptr[n + 1];
    for (int i = beg; i < end; ++i) {
        int src = col[i];
        if (c < H) {
            float e = lrelu02(es[src * H + c] + ed_sh[c]);
            float p = expf(e - m_sh[c]);
            p_sh[c] = p;
            z += p;
        }
        __syncthreads();
        const float* hp = hmid + (size_t)src * (H * C) + c;
#pragma unroll
        for (int h = 0; h < H; ++h) acc[h] += p_sh[h] * hp[h * C];
        __syncthreads();
    }
    if (c < H) z_sh[c] = z;
    __syncthreads();
    float val = 0.f;
#pragma unroll
    for (int h = 0; h < H; ++h) val += acc[h] / (z_sh[h] + 1e-16f);
    val = val * (1.f / H) + bias[c];
    val = selu_f(val);
    if (c < 2) {
        unsigned mk = masks[n];
        if (c == 0) { if (mk & 2u) val = 0.f; else if (mk & 1u) val = 1.f; }
        else        { if (mk & 8u) val = 1.f; else if (mk & 4u) val = 0.f; }
    }
    hout[(size_t)n * C + c] = val;
}

// ---------------- GAT layer 5 (H=16, C=2) fused epilogue -> d_out -----------
__global__ __launch_bounds__(256) void gat5_agg(const float* __restrict__ hmid,
                                                const float* __restrict__ es,
                                                const float* __restrict__ ed,
                                                const float* __restrict__ mx,
                                                const int* __restrict__ indptr,
                                                const int* __restrict__ col,
                                                const float* __restrict__ bias,
                                                const unsigned* __restrict__ masks,
                                                const float* __restrict__ x,
                                                float* __restrict__ out, int N) {
    const int H = 16;
    int t = threadIdx.x;
    int node = blockIdx.x * 8 + (t >> 5);
    if (node >= N) return;            // whole 32-lane group exits together
    int l = t & 31;
    int h = l >> 1, c = l & 1;
    float edv = ed[node * H + h];
    float mv  = mx[node * H + h];
    float acc = 0.f, z = 0.f;
    int beg = indptr[node], end = indptr[node + 1];
    for (int i = beg; i < end; ++i) {
        int src = col[i];
        float e = lrelu02(es[src * H + h] + edv);
        float p = expf(e - mv);
        z += p;
        acc += p * hmid[(size_t)src * 32 + l];
    }
    float val = acc / (z + 1e-16f);
#pragma unroll
    for (int off = 2; off <= 16; off <<= 1) val += __shfl_xor(val, off);
    val = val * (1.f / 16.f) + bias[c];
    val = selu_f(val);
    val = x[node * 10 + c] + val;
    unsigned mk = masks[node];
    if (c == 0) { if (mk & 2u) val = 0.f; else if (mk & 1u) val = 1.f; }
    else        { if (mk & 8u) val = 1.f; else if (mk & 4u) val = 0.f; }
    if (l < 2) out[node * 2 + c] = val;
}

// ---------------------------------------------------------------------------
extern "C" void kernel_launch(void* const* d_in, const int* in_sizes, int n_in,
                              void* d_out, int out_size, void* d_ws, size_t ws_size,
                              hipStream_t stream) {
    const float* x   = (const float*)d_in[0];
    const int*   ei  = (const int*)d_in[1];
    const float* cf  = (const float*)d_in[2];
    const float* cw[4] = {(const float*)d_in[3], (const float*)d_in[5],
                          (const float*)d_in[7], (const float*)d_in[9]};
    const float* cb[4] = {(const float*)d_in[4], (const float*)d_in[6],
                          (const float*)d_in[8], (const float*)d_in[10]};
    const float* gw[5], *gas[5], *gad[5], *gb[5];
    for (int i = 0; i < 5; ++i) {
        gw[i]  = (const float*)d_in[11 + 4 * i];
        gas[i] = (const float*)d_in[12 + 4 * i];
        gad[i] = (const float*)d_in[13 + 4 * i];
        gb[i]  = (const float*)d_in[14 + 4 * i];
    }
    const int N = in_sizes[0] / 10;        // 10000
    const int E = in_sizes[1] / 2;         // 160000
    const int EN = E + N;

    // ---- workspace carve-up (bump allocator, 256B aligned) ----
    char* base = (char*)d_ws;
    size_t off = 0;
    auto alloc = [&](size_t bytes) -> char* {
        char* p = base + off;
        off = (off + bytes + 255) & ~(size_t)255;
        return p;
    };
    float* c1   = (float*)alloc(16 * 4096 * 4);
    float* c2   = (float*)alloc(32 * 4096 * 4);
    float* c3   = (float*)alloc(64 * 4096 * 4);
    float* c4   = (float*)alloc(24 * 4096 * 4);
    float* gfeat= (float*)alloc(24 * 4);
    float* hA   = (float*)alloc((size_t)N * 256 * 4);
    float* hB   = (float*)alloc((size_t)N * 256 * 4);
    float* hmid = (float*)alloc((size_t)N * 2048 * 4);
    float* es   = (float*)alloc((size_t)N * 16 * 4);
    float* ed   = (float*)alloc((size_t)N * 16 * 4);
    float* mx   = (float*)alloc((size_t)N * 16 * 4);
    unsigned* masks = (unsigned*)alloc((size_t)N * 4);
    int* cnt    = (int*)alloc((size_t)N * 4);
    int* indptr = (int*)alloc((size_t)(N + 1) * 4);
    int* cursor = (int*)alloc((size_t)N * 4);
    int* col    = (int*)alloc((size_t)EN * 4);
    (void)ws_size; // needs ~106 MB

    // ---- CNN ----
    conv3x3_selu<<<(16 * 4096 + 255) / 256, 256, 0, stream>>>(cf, cw[0], cb[0], c1, 4, 16);
    conv3x3_selu<<<(32 * 4096 + 255) / 256, 256, 0, stream>>>(c1, cw[1], cb[1], c2, 16, 32);
    conv3x3_selu<<<(64 * 4096 + 255) / 256, 256, 0, stream>>>(c2, cw[2], cb[2], c3, 32, 64);
    conv3x3_selu<<<(24 * 4096 + 255) / 256, 256, 0, stream>>>(c3, cw[3], cb[3], c4, 64, 24);
    avgpool_c<<<24, 256, 0, stream>>>(c4, gfeat);

    // ---- h0 + masks ----
    build_h0<<<(N + 255) / 256, 256, 0, stream>>>(x, gfeat, hA, masks, N);

    // ---- CSR by dst (incl self loops) ----
    hipMemsetAsync(cnt, 0, (size_t)N * 4, stream);
    count_dst<<<(EN + 255) / 256, 256, 0, stream>>>(ei, cnt, E, N);
    exscan_single<<<1, 256, 0, stream>>>(cnt, indptr, N);
    copy_int<<<(N + 255) / 256, 256, 0, stream>>>(indptr, cursor, N);
    scatter_edges<<<(EN + 255) / 256, 256, 0, stream>>>(ei, cursor, col, E, N);

    // ---- GAT layers ----
    // layer dims: {Kin, H, C}
    const int Ks[5] = {34, 64, 128, 256, 128};
    const int Hs[5] = {8, 16, 8, 8, 16};
    const int Cs[5] = {64, 128, 256, 128, 2};
    const float* hin = hA;
    float* houts[4] = {hB, hA, hB, hA};

    for (int lyr = 0; lyr < 5; ++lyr) {
        int K = Ks[lyr], H = Hs[lyr], C = Cs[lyr], M = H * C;
        dim3 ggrid((N + BN - 1) / BN, (M + BM - 1) / BM);
        sgemm<<<ggrid, 256, 0, stream>>>(hin, gw[lyr], hmid, N, K, M);
        esed_kernel<<<N * H, 64, 0, stream>>>(hmid, gas[lyr], gad[lyr], es, ed, H, C);
        segmax_kernel<<<(N * H + 255) / 256, 256, 0, stream>>>(es, ed, indptr, col, mx, N, H);
        if (lyr == 0)
            gat_agg<8, 64><<<N, 64, 0, stream>>>(hmid, es, ed, mx, indptr, col, gb[0], masks, houts[0]);
        else if (lyr == 1)
            gat_agg<16, 128><<<N, 128, 0, stream>>>(hmid, es, ed, mx, indptr, col, gb[1], masks, houts[1]);
        else if (lyr == 2)
            gat_agg<8, 256><<<N, 256, 0, stream>>>(hmid, es, ed, mx, indptr, col, gb[2], masks, houts[2]);
        else if (lyr == 3)
            gat_agg<8, 128><<<N, 128, 0, stream>>>(hmid, es, ed, mx, indptr, col, gb[3], masks, houts[3]);
        else
            gat5_agg<<<(N + 7) / 8, 256, 0, stream>>>(hmid, es, ed, mx, indptr, col, gb[4],
                                                      masks, x, (float*)d_out, N);
        if (lyr < 4) hin = houts[lyr];
    }
}

// Round 2
// 1312.872 us; speedup vs baseline: 1.1187x; 1.1187x over previous
//
#include <hip/hip_runtime.h>
#include <math.h>

// ---------------------------------------------------------------------------
// NetGlobGATFix: CNN(4 conv3x3+selu, avgpool) -> concat(gfeat,x) -> 5x GATConv
// (softmax attention over incoming edges incl self-loops, mean over heads)
// with selu + boundary fixes between layers.
//
// R1: GEMM -> split-bf16 MFMA (hi/lo decomposition, 3 MFMA per product,
//     fp32-equivalent accuracy). Everything else unchanged from R0.
// ---------------------------------------------------------------------------

#define DEVFN static __device__ __forceinline__

typedef __attribute__((ext_vector_type(8))) short short8;
typedef __attribute__((ext_vector_type(4))) float f32x4;

DEVFN float selu_f(float v) {
    const float scale = 1.0507009873554805f;
    const float alpha = 1.6732632423543772f;
    return v > 0.f ? scale * v : scale * alpha * (expf(v) - 1.f);
}

DEVFN float lrelu02(float v) { return v > 0.f ? v : 0.2f * v; }

DEVFN void split_bf16(float a, unsigned short& hi, unsigned short& lo) {
    unsigned u = __float_as_uint(a);
    unsigned r = u + 0x7FFF + ((u >> 16) & 1);      // RNE to bf16
    unsigned short h = (unsigned short)(r >> 16);
    float hf = __uint_as_float((unsigned)h << 16);
    float l = a - hf;
    unsigned ul = __float_as_uint(l);
    unsigned rl = ul + 0x7FFF + ((ul >> 16) & 1);
    hi = h;
    lo = (unsigned short)(rl >> 16);
}

// ---------------- CNN ----------------
__global__ void conv3x3_selu(const float* __restrict__ in, const float* __restrict__ w,
                             const float* __restrict__ b, float* __restrict__ out,
                             int Cin, int Cout) {
    int t = blockIdx.x * blockDim.x + threadIdx.x;
    if (t >= Cout * 4096) return;
    int pix = t & 4095;
    int co  = t >> 12;
    int y = pix >> 6, x = pix & 63;
    float acc = b[co];
    for (int ci = 0; ci < Cin; ++ci) {
        const float* ip = in + ci * 4096;
        const float* wp = w + (co * Cin + ci) * 9;
#pragma unroll
        for (int ky = 0; ky < 3; ++ky) {
            int yy = y + ky - 1;
            if (yy < 0 || yy > 63) continue;
#pragma unroll
            for (int kx = 0; kx < 3; ++kx) {
                int xx = x + kx - 1;
                if (xx < 0 || xx > 63) continue;
                acc += ip[yy * 64 + xx] * wp[ky * 3 + kx];
            }
        }
    }
    out[t] = selu_f(acc);
}

__global__ void avgpool_c(const float* __restrict__ in, float* __restrict__ gfeat) {
    int c = blockIdx.x;            // 24 blocks
    int t = threadIdx.x;           // 256 threads
    float s = 0.f;
    for (int i = t; i < 4096; i += 256) s += in[c * 4096 + i];
#pragma unroll
    for (int off = 32; off >= 1; off >>= 1) s += __shfl_xor(s, off);
    __shared__ float red[4];
    int wave = t >> 6, lane = t & 63;
    if (lane == 0) red[wave] = s;
    __syncthreads();
    if (t == 0) gfeat[c] = (red[0] + red[1] + red[2] + red[3]) * (1.f / 4096.f);
}

// ---------------- node feature init + boundary masks ----------------
__global__ void build_h0(const float* __restrict__ x, const float* __restrict__ gfeat,
                         float* __restrict__ h0, unsigned* __restrict__ masks, int N) {
    int n = blockIdx.x * blockDim.x + threadIdx.x;
    if (n >= N) return;
    float x0 = x[n * 10 + 0], x1 = x[n * 10 + 1];
    unsigned mk = (x0 == 1.f ? 1u : 0u) | (x0 == 0.f ? 2u : 0u) |
                  (x1 == 0.f ? 4u : 0u) | (x1 == 1.f ? 8u : 0u);
    masks[n] = mk;
    float* hp = h0 + (size_t)n * 34;
#pragma unroll
    for (int j = 0; j < 24; ++j) hp[j] = gfeat[j];
#pragma unroll
    for (int j = 0; j < 10; ++j) hp[24 + j] = x[n * 10 + j];
}

// ---------------- CSR build ----------------
__global__ void count_dst(const int* __restrict__ ei, int* __restrict__ cnt, int E, int N) {
    int t = blockIdx.x * blockDim.x + threadIdx.x;
    if (t >= E + N) return;
    int dst = (t < E) ? ei[E + t] : (t - E);
    atomicAdd(&cnt[dst], 1);
}

__global__ void exscan_single(const int* __restrict__ cnt, int* __restrict__ indptr, int n) {
    __shared__ int sdata[256];
    __shared__ int run_s;
    int tid = threadIdx.x;
    if (tid == 0) { run_s = 0; indptr[0] = 0; }
    __syncthreads();
    for (int base = 0; base < n; base += 256) {
        int i = base + tid;
        int v = (i < n) ? cnt[i] : 0;
        sdata[tid] = v;
        __syncthreads();
        for (int off = 1; off < 256; off <<= 1) {
            int tmp = (tid >= off) ? sdata[tid - off] : 0;
            __syncthreads();
            sdata[tid] += tmp;
            __syncthreads();
        }
        if (i < n) indptr[i + 1] = run_s + sdata[tid];
        __syncthreads();
        if (tid == 0) run_s += sdata[255];
        __syncthreads();
    }
}

__global__ void copy_int(const int* __restrict__ a, int* __restrict__ b, int n) {
    int t = blockIdx.x * blockDim.x + threadIdx.x;
    if (t < n) b[t] = a[t];
}

__global__ void scatter_edges(const int* __restrict__ ei, int* __restrict__ cursor,
                              int* __restrict__ col, int E, int N) {
    int t = blockIdx.x * blockDim.x + threadIdx.x;
    if (t >= E + N) return;
    int src, dst;
    if (t < E) { src = ei[t]; dst = ei[E + t]; }
    else       { src = dst = t - E; }
    int pos = atomicAdd(&cursor[dst], 1);
    col[pos] = src;
}

// ---------------- GEMM via split-bf16 MFMA ----------------------------------
// C[N,M] = A[N,K] @ B[K,M], fp32 in/out, fp32-equivalent accuracy via
// a=ah+al, b=bh+bl; acc += ah*bh + ah*bl + al*bh  (3x mfma_f32_16x16x32_bf16).
// Block tile 64x64, 4 waves; wave w owns rows [w*16,w*16+16) x all 64 cols.
#define LDP 40   // LDS row stride in shorts (80B = 20 banks -> 2-way, free)
__global__ __launch_bounds__(256) void gemm_mfma(const float* __restrict__ A,
                                                 const float* __restrict__ B,
                                                 float* __restrict__ Cm,
                                                 int N, int K, int M) {
    __shared__ __attribute__((aligned(16))) unsigned short As_hi[64 * LDP];
    __shared__ __attribute__((aligned(16))) unsigned short As_lo[64 * LDP];
    __shared__ __attribute__((aligned(16))) unsigned short Bs_hi[64 * LDP];
    __shared__ __attribute__((aligned(16))) unsigned short Bs_lo[64 * LDP];

    int tid  = threadIdx.x;
    int wave = tid >> 6;
    int lane = tid & 63;
    int ln16 = lane & 15;
    int koff = (lane >> 4) * 8;          // A[m][k]: m=lane&15, k=quad*8+j
    int row0 = blockIdx.x * 64;
    int col0 = blockIdx.y * 64;

    f32x4 acc[4];
#pragma unroll
    for (int j = 0; j < 4; ++j) acc[j] = (f32x4){0.f, 0.f, 0.f, 0.f};

    for (int k0 = 0; k0 < K; k0 += 32) {
        // stage A tile (64 rows x 32 k) with hi/lo split
        for (int idx = tid; idx < 64 * 32; idx += 256) {
            int k = idx & 31, r = idx >> 5;
            int gr = row0 + r, gk = k0 + k;
            float a = (gr < N && gk < K) ? A[(size_t)gr * K + gk] : 0.f;
            unsigned short h, l;
            split_bf16(a, h, l);
            As_hi[r * LDP + k] = h;
            As_lo[r * LDP + k] = l;
        }
        // stage B tile (32 k x 64 n), transposed to [n][k]
        for (int idx = tid; idx < 32 * 64; idx += 256) {
            int n = idx & 63, k = idx >> 6;
            int gk = k0 + k, gc = col0 + n;
            float b = (gk < K && gc < M) ? B[(size_t)gk * M + gc] : 0.f;
            unsigned short h, l;
            split_bf16(b, h, l);
            Bs_hi[n * LDP + k] = h;
            Bs_lo[n * LDP + k] = l;
        }
        __syncthreads();

        int am = wave * 16 + ln16;
        short8 ah = *(const short8*)&As_hi[am * LDP + koff];
        short8 al = *(const short8*)&As_lo[am * LDP + koff];
#pragma unroll
        for (int j = 0; j < 4; ++j) {
            int bn = j * 16 + ln16;
            short8 bh = *(const short8*)&Bs_hi[bn * LDP + koff];
            short8 bl = *(const short8*)&Bs_lo[bn * LDP + koff];
            acc[j] = __builtin_amdgcn_mfma_f32_16x16x32_bf16(ah, bh, acc[j], 0, 0, 0);
            acc[j] = __builtin_amdgcn_mfma_f32_16x16x32_bf16(ah, bl, acc[j], 0, 0, 0);
            acc[j] = __builtin_amdgcn_mfma_f32_16x16x32_bf16(al, bh, acc[j], 0, 0, 0);
        }
        __syncthreads();
    }

    // C/D layout: col = lane&15, row = (lane>>4)*4 + reg
#pragma unroll
    for (int j = 0; j < 4; ++j) {
        int cc = col0 + j * 16 + ln16;
        if (cc >= M) continue;
#pragma unroll
        for (int r = 0; r < 4; ++r) {
            int rr = row0 + wave * 16 + (lane >> 4) * 4 + r;
            if (rr < N) Cm[(size_t)rr * M + cc] = acc[j][r];
        }
    }
}

// ---------------- es/ed: per (node, head) dot products ----------------
__global__ void esed_kernel(const float* __restrict__ hmid, const float* __restrict__ as,
                            const float* __restrict__ ad, float* __restrict__ es,
                            float* __restrict__ ed, int H, int C) {
    int b = blockIdx.x;            // n*H + h
    int h = b % H;
    int lane = threadIdx.x;        // 64
    const float* hp = hmid + (size_t)b * C;   // (n*H + h) * C
    float s = 0.f, d = 0.f;
    for (int c = lane; c < C; c += 64) {
        float v = hp[c];
        s += v * as[h * C + c];
        d += v * ad[h * C + c];
    }
#pragma unroll
    for (int off = 32; off >= 1; off >>= 1) {
        s += __shfl_xor(s, off);
        d += __shfl_xor(d, off);
    }
    if (lane == 0) { es[b] = s; ed[b] = d; }
}

// ---------------- segment max over incoming edges ----------------
__global__ void segmax_kernel(const float* __restrict__ es, const float* __restrict__ ed,
                              const int* __restrict__ indptr, const int* __restrict__ col,
                              float* __restrict__ mx, int N, int H) {
    int t = blockIdx.x * blockDim.x + threadIdx.x;
    if (t >= N * H) return;
    int n = t / H, h = t - n * H;
    float edv = ed[t];
    float mv = -3.4e38f;
    int beg = indptr[n], end = indptr[n + 1];
    for (int i = beg; i < end; ++i) {
        float e = lrelu02(es[col[i] * H + h] + edv);
        mv = fmaxf(mv, e);
    }
    mx[t] = mv;
}

// ---------------- GAT aggregation (C >= 64 layers): one node per block ------
template <int H, int C>
__global__ void gat_agg(const float* __restrict__ hmid, const float* __restrict__ es,
                        const float* __restrict__ ed, const float* __restrict__ mx,
                        const int* __restrict__ indptr, const int* __restrict__ col,
                        const float* __restrict__ bias, const unsigned* __restrict__ masks,
                        float* __restrict__ hout) {
    int n = blockIdx.x;
    int c = threadIdx.x;           // blockDim = C, C >= H
    __shared__ float p_sh[H], ed_sh[H], m_sh[H], z_sh[H];
    if (c < H) {
        ed_sh[c] = ed[n * H + c];
        m_sh[c]  = mx[n * H + c];
    }
    float acc[H];
#pragma unroll
    for (int h = 0; h < H; ++h) acc[h] = 0.f;
    float z = 0.f;
    __syncthreads();
    int beg = indptr[n], end = indptr[n + 1];
    for (int i = beg; i < end; ++i) {
        int src = col[i];
        if (c < H) {
            float e = lrelu02(es[src * H + c] + ed_sh[c]);
            float p = expf(e - m_sh[c]);
            p_sh[c] = p;
            z += p;
        }
        __syncthreads();
        const float* hp = hmid + (size_t)src * (H * C) + c;
#pragma unroll
        for (int h = 0; h < H; ++h) acc[h] += p_sh[h] * hp[h * C];
        __syncthreads();
    }
    if (c < H) z_sh[c] = z;
    __syncthreads();
    float val = 0.f;
#pragma unroll
    for (int h = 0; h < H; ++h) val += acc[h] / (z_sh[h] + 1e-16f);
    val = val * (1.f / H) + bias[c];
    val = selu_f(val);
    if (c < 2) {
        unsigned mk = masks[n];
        if (c == 0) { if (mk & 2u) val = 0.f; else if (mk & 1u) val = 1.f; }
        else        { if (mk & 8u) val = 1.f; else if (mk & 4u) val = 0.f; }
    }
    hout[(size_t)n * C + c] = val;
}

// ---------------- GAT layer 5 (H=16, C=2) fused epilogue -> d_out -----------
__global__ __launch_bounds__(256) void gat5_agg(const float* __restrict__ hmid,
                                                const float* __restrict__ es,
                                                const float* __restrict__ ed,
                                                const float* __restrict__ mx,
                                                const int* __restrict__ indptr,
                                                const int* __restrict__ col,
                                                const float* __restrict__ bias,
                                                const unsigned* __restrict__ masks,
                                                const float* __restrict__ x,
                                                float* __restrict__ out, int N) {
    const int H = 16;
    int t = threadIdx.x;
    int node = blockIdx.x * 8 + (t >> 5);
    if (node >= N) return;            // whole 32-lane group exits together
    int l = t & 31;
    int h = l >> 1, c = l & 1;
    float edv = ed[node * H + h];
    float mv  = mx[node * H + h];
    float acc = 0.f, z = 0.f;
    int beg = indptr[node], end = indptr[node + 1];
    for (int i = beg; i < end; ++i) {
        int src = col[i];
        float e = lrelu02(es[src * H + h] + edv);
        float p = expf(e - mv);
        z += p;
        acc += p * hmid[(size_t)src * 32 + l];
    }
    float val = acc / (z + 1e-16f);
#pragma unroll
    for (int off = 2; off <= 16; off <<= 1) val += __shfl_xor(val, off);
    val = val * (1.f / 16.f) + bias[c];
    val = selu_f(val);
    val = x[node * 10 + c] + val;
    unsigned mk = masks[node];
    if (c == 0) { if (mk & 2u) val = 0.f; else if (mk & 1u) val = 1.f; }
    else        { if (mk & 8u) val = 1.f; else if (mk & 4u) val = 0.f; }
    if (l < 2) out[node * 2 + c] = val;
}

// ---------------------------------------------------------------------------
extern "C" void kernel_launch(void* const* d_in, const int* in_sizes, int n_in,
                              void* d_out, int out_size, void* d_ws, size_t ws_size,
                              hipStream_t stream) {
    const float* x   = (const float*)d_in[0];
    const int*   ei  = (const int*)d_in[1];
    const float* cf  = (const float*)d_in[2];
    const float* cw[4] = {(const float*)d_in[3], (const float*)d_in[5],
                          (const float*)d_in[7], (const float*)d_in[9]};
    const float* cb[4] = {(const float*)d_in[4], (const float*)d_in[6],
                          (const float*)d_in[8], (const float*)d_in[10]};
    const float* gw[5], *gas[5], *gad[5], *gb[5];
    for (int i = 0; i < 5; ++i) {
        gw[i]  = (const float*)d_in[11 + 4 * i];
        gas[i] = (const float*)d_in[12 + 4 * i];
        gad[i] = (const float*)d_in[13 + 4 * i];
        gb[i]  = (const float*)d_in[14 + 4 * i];
    }
    const int N = in_sizes[0] / 10;        // 10000
    const int E = in_sizes[1] / 2;         // 160000
    const int EN = E + N;

    // ---- workspace carve-up (bump allocator, 256B aligned) ----
    char* base = (char*)d_ws;
    size_t off = 0;
    auto alloc = [&](size_t bytes) -> char* {
        char* p = base + off;
        off = (off + bytes + 255) & ~(size_t)255;
        return p;
    };
    float* c1   = (float*)alloc(16 * 4096 * 4);
    float* c2   = (float*)alloc(32 * 4096 * 4);
    float* c3   = (float*)alloc(64 * 4096 * 4);
    float* c4   = (float*)alloc(24 * 4096 * 4);
    float* gfeat= (float*)alloc(24 * 4);
    float* hA   = (float*)alloc((size_t)N * 256 * 4);
    float* hB   = (float*)alloc((size_t)N * 256 * 4);
    float* hmid = (float*)alloc((size_t)N * 2048 * 4);
    float* es   = (float*)alloc((size_t)N * 16 * 4);
    float* ed   = (float*)alloc((size_t)N * 16 * 4);
    float* mx   = (float*)alloc((size_t)N * 16 * 4);
    unsigned* masks = (unsigned*)alloc((size_t)N * 4);
    int* cnt    = (int*)alloc((size_t)N * 4);
    int* indptr = (int*)alloc((size_t)(N + 1) * 4);
    int* cursor = (int*)alloc((size_t)N * 4);
    int* col    = (int*)alloc((size_t)EN * 4);
    (void)ws_size; // needs ~106 MB

    // ---- CNN ----
    conv3x3_selu<<<(16 * 4096 + 255) / 256, 256, 0, stream>>>(cf, cw[0], cb[0], c1, 4, 16);
    conv3x3_selu<<<(32 * 4096 + 255) / 256, 256, 0, stream>>>(c1, cw[1], cb[1], c2, 16, 32);
    conv3x3_selu<<<(64 * 4096 + 255) / 256, 256, 0, stream>>>(c2, cw[2], cb[2], c3, 32, 64);
    conv3x3_selu<<<(24 * 4096 + 255) / 256, 256, 0, stream>>>(c3, cw[3], cb[3], c4, 64, 24);
    avgpool_c<<<24, 256, 0, stream>>>(c4, gfeat);

    // ---- h0 + masks ----
    build_h0<<<(N + 255) / 256, 256, 0, stream>>>(x, gfeat, hA, masks, N);

    // ---- CSR by dst (incl self loops) ----
    hipMemsetAsync(cnt, 0, (size_t)N * 4, stream);
    count_dst<<<(EN + 255) / 256, 256, 0, stream>>>(ei, cnt, E, N);
    exscan_single<<<1, 256, 0, stream>>>(cnt, indptr, N);
    copy_int<<<(N + 255) / 256, 256, 0, stream>>>(indptr, cursor, N);
    scatter_edges<<<(EN + 255) / 256, 256, 0, stream>>>(ei, cursor, col, E, N);

    // ---- GAT layers ----
    const int Ks[5] = {34, 64, 128, 256, 128};
    const int Hs[5] = {8, 16, 8, 8, 16};
    const int Cs[5] = {64, 128, 256, 128, 2};
    const float* hin = hA;
    float* houts[4] = {hB, hA, hB, hA};

    for (int lyr = 0; lyr < 5; ++lyr) {
        int K = Ks[lyr], H = Hs[lyr], C = Cs[lyr], M = H * C;
        dim3 ggrid((N + 63) / 64, (M + 63) / 64);
        gemm_mfma<<<ggrid, 256, 0, stream>>>(hin, gw[lyr], hmid, N, K, M);
        esed_kernel<<<N * H, 64, 0, stream>>>(hmid, gas[lyr], gad[lyr], es, ed, H, C);
        segmax_kernel<<<(N * H + 255) / 256, 256, 0, stream>>>(es, ed, indptr, col, mx, N, H);
        if (lyr == 0)
            gat_agg<8, 64><<<N, 64, 0, stream>>>(hmid, es, ed, mx, indptr, col, gb[0], masks, houts[0]);
        else if (lyr == 1)
            gat_agg<16, 128><<<N, 128, 0, stream>>>(hmid, es, ed, mx, indptr, col, gb[1], masks, houts[1]);
        else if (lyr == 2)
            gat_agg<8, 256><<<N, 256, 0, stream>>>(hmid, es, ed, mx, indptr, col, gb[2], masks, houts[2]);
        else if (lyr == 3)
            gat_agg<8, 128><<<N, 128, 0, stream>>>(hmid, es, ed, mx, indptr, col, gb[3], masks, houts[3]);
        else
            gat5_agg<<<(N + 7) / 8, 256, 0, stream>>>(hmid, es, ed, mx, indptr, col, gb[4],
                                                      masks, x, (float*)d_out, N);
        if (lyr < 4) hin = houts[lyr];
    }
}

// Round 3
// 1100.904 us; speedup vs baseline: 1.3341x; 1.1925x over previous
//
#include <hip/hip_runtime.h>
#include <hip/hip_fp16.h>
#include <math.h>

// ---------------------------------------------------------------------------
// NetGlobGATFix. R2:
//  - hmid stored fp16 (half gather bytes; 41 MB ~ L2-resident)
//  - attn_kernel precomputes per-edge softmax numerators palpha + zinv
//    -> gat_agg is a barrier-free gather-FMA loop (half2 vectorized)
//  - GEMM: cheaper truncation hi/lo split (residual exact), fp16 epilogue
// ---------------------------------------------------------------------------

#define DEVFN static __device__ __forceinline__

typedef __attribute__((ext_vector_type(8))) short short8;
typedef __attribute__((ext_vector_type(4))) float f32x4;

DEVFN float selu_f(float v) {
    const float scale = 1.0507009873554805f;
    const float alpha = 1.6732632423543772f;
    return v > 0.f ? scale * v : scale * alpha * (expf(v) - 1.f);
}

DEVFN float lrelu02(float v) { return v > 0.f ? v : 0.2f * v; }

// truncation split: hi = trunc_bf16(a); lo = trunc_bf16(a - hi) (a-hi exact)
DEVFN void split_bf16(float a, unsigned short& hi, unsigned short& lo) {
    unsigned u = __float_as_uint(a);
    hi = (unsigned short)(u >> 16);
    float hf = __uint_as_float(u & 0xFFFF0000u);
    float l = a - hf;
    lo = (unsigned short)(__float_as_uint(l) >> 16);
}

// ---------------- CNN ----------------
__global__ void conv3x3_selu(const float* __restrict__ in, const float* __restrict__ w,
                             const float* __restrict__ b, float* __restrict__ out,
                             int Cin, int Cout) {
    int t = blockIdx.x * blockDim.x + threadIdx.x;
    if (t >= Cout * 4096) return;
    int pix = t & 4095;
    int co  = t >> 12;
    int y = pix >> 6, x = pix & 63;
    float acc = b[co];
    for (int ci = 0; ci < Cin; ++ci) {
        const float* ip = in + ci * 4096;
        const float* wp = w + (co * Cin + ci) * 9;
#pragma unroll
        for (int ky = 0; ky < 3; ++ky) {
            int yy = y + ky - 1;
            if (yy < 0 || yy > 63) continue;
#pragma unroll
            for (int kx = 0; kx < 3; ++kx) {
                int xx = x + kx - 1;
                if (xx < 0 || xx > 63) continue;
                acc += ip[yy * 64 + xx] * wp[ky * 3 + kx];
            }
        }
    }
    out[t] = selu_f(acc);
}

__global__ void avgpool_c(const float* __restrict__ in, float* __restrict__ gfeat) {
    int c = blockIdx.x;            // 24 blocks
    int t = threadIdx.x;           // 256 threads
    float s = 0.f;
    for (int i = t; i < 4096; i += 256) s += in[c * 4096 + i];
#pragma unroll
    for (int off = 32; off >= 1; off >>= 1) s += __shfl_xor(s, off);
    __shared__ float red[4];
    int wave = t >> 6, lane = t & 63;
    if (lane == 0) red[wave] = s;
    __syncthreads();
    if (t == 0) gfeat[c] = (red[0] + red[1] + red[2] + red[3]) * (1.f / 4096.f);
}

// ---------------- node feature init + boundary masks ----------------
__global__ void build_h0(const float* __restrict__ x, const float* __restrict__ gfeat,
                         float* __restrict__ h0, unsigned* __restrict__ masks, int N) {
    int n = blockIdx.x * blockDim.x + threadIdx.x;
    if (n >= N) return;
    float x0 = x[n * 10 + 0], x1 = x[n * 10 + 1];
    unsigned mk = (x0 == 1.f ? 1u : 0u) | (x0 == 0.f ? 2u : 0u) |
                  (x1 == 0.f ? 4u : 0u) | (x1 == 1.f ? 8u : 0u);
    masks[n] = mk;
    float* hp = h0 + (size_t)n * 34;
#pragma unroll
    for (int j = 0; j < 24; ++j) hp[j] = gfeat[j];
#pragma unroll
    for (int j = 0; j < 10; ++j) hp[24 + j] = x[n * 10 + j];
}

// ---------------- CSR build ----------------
__global__ void count_dst(const int* __restrict__ ei, int* __restrict__ cnt, int E, int N) {
    int t = blockIdx.x * blockDim.x + threadIdx.x;
    if (t >= E + N) return;
    int dst = (t < E) ? ei[E + t] : (t - E);
    atomicAdd(&cnt[dst], 1);
}

__global__ void exscan_single(const int* __restrict__ cnt, int* __restrict__ indptr, int n) {
    __shared__ int sdata[256];
    __shared__ int run_s;
    int tid = threadIdx.x;
    if (tid == 0) { run_s = 0; indptr[0] = 0; }
    __syncthreads();
    for (int base = 0; base < n; base += 256) {
        int i = base + tid;
        int v = (i < n) ? cnt[i] : 0;
        sdata[tid] = v;
        __syncthreads();
        for (int off = 1; off < 256; off <<= 1) {
            int tmp = (tid >= off) ? sdata[tid - off] : 0;
            __syncthreads();
            sdata[tid] += tmp;
            __syncthreads();
        }
        if (i < n) indptr[i + 1] = run_s + sdata[tid];
        __syncthreads();
        if (tid == 0) run_s += sdata[255];
        __syncthreads();
    }
}

__global__ void copy_int(const int* __restrict__ a, int* __restrict__ b, int n) {
    int t = blockIdx.x * blockDim.x + threadIdx.x;
    if (t < n) b[t] = a[t];
}

__global__ void scatter_edges(const int* __restrict__ ei, int* __restrict__ cursor,
                              int* __restrict__ col, int E, int N) {
    int t = blockIdx.x * blockDim.x + threadIdx.x;
    if (t >= E + N) return;
    int src, dst;
    if (t < E) { src = ei[t]; dst = ei[E + t]; }
    else       { src = dst = t - E; }
    int pos = atomicAdd(&cursor[dst], 1);
    col[pos] = src;
}

// ---------------- GEMM via split-bf16 MFMA, fp16 epilogue -------------------
#define LDP 40
__global__ __launch_bounds__(256) void gemm_mfma(const float* __restrict__ A,
                                                 const float* __restrict__ B,
                                                 __half* __restrict__ Cm,
                                                 int N, int K, int M) {
    __shared__ __attribute__((aligned(16))) unsigned short As_hi[64 * LDP];
    __shared__ __attribute__((aligned(16))) unsigned short As_lo[64 * LDP];
    __shared__ __attribute__((aligned(16))) unsigned short Bs_hi[64 * LDP];
    __shared__ __attribute__((aligned(16))) unsigned short Bs_lo[64 * LDP];

    int tid  = threadIdx.x;
    int wave = tid >> 6;
    int lane = tid & 63;
    int ln16 = lane & 15;
    int koff = (lane >> 4) * 8;
    int row0 = blockIdx.x * 64;
    int col0 = blockIdx.y * 64;

    f32x4 acc[4];
#pragma unroll
    for (int j = 0; j < 4; ++j) acc[j] = (f32x4){0.f, 0.f, 0.f, 0.f};

    for (int k0 = 0; k0 < K; k0 += 32) {
        for (int idx = tid; idx < 64 * 32; idx += 256) {
            int k = idx & 31, r = idx >> 5;
            int gr = row0 + r, gk = k0 + k;
            float a = (gr < N && gk < K) ? A[(size_t)gr * K + gk] : 0.f;
            unsigned short h, l;
            split_bf16(a, h, l);
            As_hi[r * LDP + k] = h;
            As_lo[r * LDP + k] = l;
        }
        for (int idx = tid; idx < 32 * 64; idx += 256) {
            int n = idx & 63, k = idx >> 6;
            int gk = k0 + k, gc = col0 + n;
            float b = (gk < K && gc < M) ? B[(size_t)gk * M + gc] : 0.f;
            unsigned short h, l;
            split_bf16(b, h, l);
            Bs_hi[n * LDP + k] = h;
            Bs_lo[n * LDP + k] = l;
        }
        __syncthreads();

        int am = wave * 16 + ln16;
        short8 ah = *(const short8*)&As_hi[am * LDP + koff];
        short8 al = *(const short8*)&As_lo[am * LDP + koff];
#pragma unroll
        for (int j = 0; j < 4; ++j) {
            int bn = j * 16 + ln16;
            short8 bh = *(const short8*)&Bs_hi[bn * LDP + koff];
            short8 bl = *(const short8*)&Bs_lo[bn * LDP + koff];
            acc[j] = __builtin_amdgcn_mfma_f32_16x16x32_bf16(ah, bh, acc[j], 0, 0, 0);
            acc[j] = __builtin_amdgcn_mfma_f32_16x16x32_bf16(ah, bl, acc[j], 0, 0, 0);
            acc[j] = __builtin_amdgcn_mfma_f32_16x16x32_bf16(al, bh, acc[j], 0, 0, 0);
        }
        __syncthreads();
    }

    // C/D layout: col = lane&15, row = (lane>>4)*4 + reg
#pragma unroll
    for (int j = 0; j < 4; ++j) {
        int cc = col0 + j * 16 + ln16;
        if (cc >= M) continue;
#pragma unroll
        for (int r = 0; r < 4; ++r) {
            int rr = row0 + wave * 16 + (lane >> 4) * 4 + r;
            if (rr < N) Cm[(size_t)rr * M + cc] = __float2half(acc[j][r]);
        }
    }
}

// ---------------- es/ed: per (node, head) dot products (fp16 hmid) ---------
__global__ void esed_kernel(const __half* __restrict__ hmid, const float* __restrict__ as,
                            const float* __restrict__ ad, float* __restrict__ es,
                            float* __restrict__ ed, int H, int C) {
    int b = blockIdx.x;            // n*H + h
    int h = b % H;
    int lane = threadIdx.x;        // 64
    const __half* hp = hmid + (size_t)b * C;
    float s = 0.f, d = 0.f;
    for (int c = lane; c < C; c += 64) {
        float v = __half2float(hp[c]);
        s += v * as[h * C + c];
        d += v * ad[h * C + c];
    }
#pragma unroll
    for (int off = 32; off >= 1; off >>= 1) {
        s += __shfl_xor(s, off);
        d += __shfl_xor(d, off);
    }
    if (lane == 0) { es[b] = s; ed[b] = d; }
}

// ---------------- attention: segmax + per-edge numerators + 1/z ------------
__global__ void attn_kernel(const float* __restrict__ es, const float* __restrict__ ed,
                            const int* __restrict__ indptr, const int* __restrict__ col,
                            float* __restrict__ palpha, float* __restrict__ zinv,
                            int N, int H) {
    int t = blockIdx.x * blockDim.x + threadIdx.x;
    if (t >= N * H) return;
    int n = t / H, h = t - n * H;
    float edv = ed[t];
    int beg = indptr[n], end = indptr[n + 1];
    float mv = -3.4e38f;
    for (int i = beg; i < end; ++i) {
        float e = lrelu02(es[col[i] * H + h] + edv);
        mv = fmaxf(mv, e);
    }
    float z = 0.f;
    for (int i = beg; i < end; ++i) {
        float e = lrelu02(es[col[i] * H + h] + edv);
        float p = expf(e - mv);
        palpha[(size_t)i * H + h] = p;
        z += p;
    }
    zinv[t] = 1.f / (z + 1e-16f);
}

// ---------------- GAT aggregation: barrier-free gather-FMA ------------------
// VEC=2 channels/thread (half2), NPB nodes per block.
template <int H, int C, int NPB>
__global__ __launch_bounds__(128) void gat_agg(const __half* __restrict__ hmid,
                                               const float* __restrict__ palpha,
                                               const float* __restrict__ zinv,
                                               const int* __restrict__ indptr,
                                               const int* __restrict__ col,
                                               const float* __restrict__ bias,
                                               const unsigned* __restrict__ masks,
                                               float* __restrict__ hout, int N) {
    const int TPN = C / 2;                      // threads per node
    int sub = threadIdx.x / TPN;
    int j   = threadIdx.x % TPN;
    int n = blockIdx.x * NPB + sub;
    if (n >= N) return;
    int c0 = j * 2;
    float acc[H][2];
#pragma unroll
    for (int h = 0; h < H; ++h) { acc[h][0] = 0.f; acc[h][1] = 0.f; }
    int beg = indptr[n], end = indptr[n + 1];
    for (int i = beg; i < end; ++i) {
        int src = col[i];
        const __half* hp = hmid + (size_t)src * (H * C) + c0;
        const float* ap = palpha + (size_t)i * H;
#pragma unroll
        for (int h = 0; h < H; ++h) {
            float a = ap[h];
            __half2 hv = *(const __half2*)(hp + h * C);
            float2 f = __half22float2(hv);
            acc[h][0] += a * f.x;
            acc[h][1] += a * f.y;
        }
    }
    float zv[H];
#pragma unroll
    for (int h = 0; h < H; ++h) zv[h] = zinv[n * H + h];
    unsigned mk = masks[n];
#pragma unroll
    for (int v = 0; v < 2; ++v) {
        int c = c0 + v;
        float val = 0.f;
#pragma unroll
        for (int h = 0; h < H; ++h) val += acc[h][v] * zv[h];
        val = val * (1.f / H) + bias[c];
        val = selu_f(val);
        if (c == 0) { if (mk & 2u) val = 0.f; else if (mk & 1u) val = 1.f; }
        if (c == 1) { if (mk & 8u) val = 1.f; else if (mk & 4u) val = 0.f; }
        hout[(size_t)n * C + c] = val;
    }
}

// ---------------- GAT layer 5 (H=16, C=2) fused epilogue -> d_out -----------
__global__ __launch_bounds__(256) void gat5_agg(const __half* __restrict__ hmid,
                                                const float* __restrict__ palpha,
                                                const float* __restrict__ zinv,
                                                const int* __restrict__ indptr,
                                                const int* __restrict__ col,
                                                const float* __restrict__ bias,
                                                const unsigned* __restrict__ masks,
                                                const float* __restrict__ x,
                                                float* __restrict__ out, int N) {
    const int H = 16;
    int t = threadIdx.x;
    int node = blockIdx.x * 8 + (t >> 5);
    if (node >= N) return;
    int l = t & 31;
    int h = l >> 1, c = l & 1;
    float acc = 0.f;
    int beg = indptr[node], end = indptr[node + 1];
    for (int i = beg; i < end; ++i) {
        int src = col[i];
        acc += palpha[(size_t)i * H + h] * __half2float(hmid[(size_t)src * 32 + l]);
    }
    float val = acc * zinv[node * H + h];
#pragma unroll
    for (int off = 2; off <= 16; off <<= 1) val += __shfl_xor(val, off);
    val = val * (1.f / 16.f) + bias[c];
    val = selu_f(val);
    val = x[node * 10 + c] + val;
    unsigned mk = masks[node];
    if (c == 0) { if (mk & 2u) val = 0.f; else if (mk & 1u) val = 1.f; }
    else        { if (mk & 8u) val = 1.f; else if (mk & 4u) val = 0.f; }
    if (l < 2) out[node * 2 + c] = val;
}

// ---------------------------------------------------------------------------
extern "C" void kernel_launch(void* const* d_in, const int* in_sizes, int n_in,
                              void* d_out, int out_size, void* d_ws, size_t ws_size,
                              hipStream_t stream) {
    const float* x   = (const float*)d_in[0];
    const int*   ei  = (const int*)d_in[1];
    const float* cf  = (const float*)d_in[2];
    const float* cw[4] = {(const float*)d_in[3], (const float*)d_in[5],
                          (const float*)d_in[7], (const float*)d_in[9]};
    const float* cb[4] = {(const float*)d_in[4], (const float*)d_in[6],
                          (const float*)d_in[8], (const float*)d_in[10]};
    const float* gw[5], *gas[5], *gad[5], *gb[5];
    for (int i = 0; i < 5; ++i) {
        gw[i]  = (const float*)d_in[11 + 4 * i];
        gas[i] = (const float*)d_in[12 + 4 * i];
        gad[i] = (const float*)d_in[13 + 4 * i];
        gb[i]  = (const float*)d_in[14 + 4 * i];
    }
    const int N = in_sizes[0] / 10;        // 10000
    const int E = in_sizes[1] / 2;         // 160000
    const int EN = E + N;

    // ---- workspace carve-up ----
    char* base = (char*)d_ws;
    size_t off = 0;
    auto alloc = [&](size_t bytes) -> char* {
        char* p = base + off;
        off = (off + bytes + 255) & ~(size_t)255;
        return p;
    };
    float* c1   = (float*)alloc(16 * 4096 * 4);
    float* c2   = (float*)alloc(32 * 4096 * 4);
    float* c3   = (float*)alloc(64 * 4096 * 4);
    float* c4   = (float*)alloc(24 * 4096 * 4);
    float* gfeat= (float*)alloc(24 * 4);
    float* hA   = (float*)alloc((size_t)N * 256 * 4);
    float* hB   = (float*)alloc((size_t)N * 256 * 4);
    __half* hmid= (__half*)alloc((size_t)N * 2048 * 2);
    float* es   = (float*)alloc((size_t)N * 16 * 4);
    float* ed   = (float*)alloc((size_t)N * 16 * 4);
    float* zinv = (float*)alloc((size_t)N * 16 * 4);
    float* palpha = (float*)alloc((size_t)EN * 16 * 4);
    unsigned* masks = (unsigned*)alloc((size_t)N * 4);
    int* cnt    = (int*)alloc((size_t)N * 4);
    int* indptr = (int*)alloc((size_t)(N + 1) * 4);
    int* cursor = (int*)alloc((size_t)N * 4);
    int* col    = (int*)alloc((size_t)EN * 4);
    (void)ws_size; // ~77 MB

    // ---- CNN ----
    conv3x3_selu<<<(16 * 4096 + 255) / 256, 256, 0, stream>>>(cf, cw[0], cb[0], c1, 4, 16);
    conv3x3_selu<<<(32 * 4096 + 255) / 256, 256, 0, stream>>>(c1, cw[1], cb[1], c2, 16, 32);
    conv3x3_selu<<<(64 * 4096 + 255) / 256, 256, 0, stream>>>(c2, cw[2], cb[2], c3, 32, 64);
    conv3x3_selu<<<(24 * 4096 + 255) / 256, 256, 0, stream>>>(c3, cw[3], cb[3], c4, 64, 24);
    avgpool_c<<<24, 256, 0, stream>>>(c4, gfeat);

    // ---- h0 + masks ----
    build_h0<<<(N + 255) / 256, 256, 0, stream>>>(x, gfeat, hA, masks, N);

    // ---- CSR by dst (incl self loops) ----
    hipMemsetAsync(cnt, 0, (size_t)N * 4, stream);
    count_dst<<<(EN + 255) / 256, 256, 0, stream>>>(ei, cnt, E, N);
    exscan_single<<<1, 256, 0, stream>>>(cnt, indptr, N);
    copy_int<<<(N + 255) / 256, 256, 0, stream>>>(indptr, cursor, N);
    scatter_edges<<<(EN + 255) / 256, 256, 0, stream>>>(ei, cursor, col, E, N);

    // ---- GAT layers ----
    const int Ks[5] = {34, 64, 128, 256, 128};
    const int Hs[5] = {8, 16, 8, 8, 16};
    const int Cs[5] = {64, 128, 256, 128, 2};
    const float* hin = hA;
    float* houts[4] = {hB, hA, hB, hA};

    for (int lyr = 0; lyr < 5; ++lyr) {
        int K = Ks[lyr], H = Hs[lyr], C = Cs[lyr], M = H * C;
        dim3 ggrid((N + 63) / 64, (M + 63) / 64);
        gemm_mfma<<<ggrid, 256, 0, stream>>>(hin, gw[lyr], hmid, N, K, M);
        esed_kernel<<<N * H, 64, 0, stream>>>(hmid, gas[lyr], gad[lyr], es, ed, H, C);
        attn_kernel<<<(N * H + 255) / 256, 256, 0, stream>>>(es, ed, indptr, col,
                                                             palpha, zinv, N, H);
        if (lyr == 0)
            gat_agg<8, 64, 4><<<(N + 3) / 4, 128, 0, stream>>>(hmid, palpha, zinv, indptr, col, gb[0], masks, houts[0], N);
        else if (lyr == 1)
            gat_agg<16, 128, 2><<<(N + 1) / 2, 128, 0, stream>>>(hmid, palpha, zinv, indptr, col, gb[1], masks, houts[1], N);
        else if (lyr == 2)
            gat_agg<8, 256, 1><<<N, 128, 0, stream>>>(hmid, palpha, zinv, indptr, col, gb[2], masks, houts[2], N);
        else if (lyr == 3)
            gat_agg<8, 128, 2><<<(N + 1) / 2, 128, 0, stream>>>(hmid, palpha, zinv, indptr, col, gb[3], masks, houts[3], N);
        else
            gat5_agg<<<(N + 7) / 8, 256, 0, stream>>>(hmid, palpha, zinv, indptr, col, gb[4],
                                                      masks, x, (float*)d_out, N);
        if (lyr < 4) hin = houts[lyr];
    }
}